// Round 1
// 322.989 us; speedup vs baseline: 1.8108x; 1.8108x over previous
//
#include <hip/hip_runtime.h>

// CostVolume: B=4,H=256,W=512,C=64,D=64.
// out[b,h,w,d] = (w-d-1>=0) ? (1/64) * sum_c L[b,h,w,c]*R[b,h,w-d-1,c] : 0
//
// R4 design: LDS-tiled banded GEMM. Block = (bh, w-tile of 128), 512 threads.
// Stage L[w0..w0+128) and R[w0-64..w0+128) into 80KB LDS (one barrier), then
// compute from LDS. Previous register-sliding-window approach was latency-bound:
// VGPR_Count=40 proved the asm pin failed (window needs >=64 VGPRs) -> compiler
// rematerialized the window as per-step global loads (~900cy serial latency,
// VALUBusy 16%, HBM 13%).
//
// Lane map: lane = (ta<<3)|tb; w = w0 + 16*ta + wp, d = 8*tb + j.
// R row u = w-1-d = (w0-64) + [63 + 16*ta - 8*tb + wp - j]: the coarse part
// 16ta-8tb gives only ~22 distinct LDS addresses per wave-read (broadcast
// dedup -> ~3 cyc/read instead of 12+), rows are stride-8 across lanes.
// LDS layout (16B cells): cell = k*NROWS + (row>>3) + (row&7)*PH  -- stride-8
// row sets become stride-1 in (row>>3) -> even bank-slot spread, and the
// fully-unrolled k-loop folds k*NROWS*16 into ds_read_b128 immediates.
// Traffic: L 1x (134MB) + R 1.5x (201MB) + out (134MB) = 470MB -> ~75us HBM floor.

#define WW 512
#define CC 64
#define DD 64
#define WT 128

typedef float f4 __attribute__((ext_vector_type(4)));

__global__ __launch_bounds__(512, 4)
void CostVolume_47433618817551_kernel(const float* __restrict__ left,
                                      const float* __restrict__ right,
                                      float* __restrict__ out) {
    const int tid = threadIdx.x;
    const int bid = blockIdx.x;
    const int bh  = bid >> 2;            // 0..1023
    const int w0  = (bid & 3) * WT;      // 0,128,256,384

    const float* Lg = left  + (size_t)bh * (WW * CC);
    const float* Rg = right + (size_t)bh * (WW * CC);
    float*       Og = out   + (size_t)bh * (WW * DD);

    // R: 16 k-chunks x 192 rows; L: 16 k-chunks x 128 rows. 5120 cells * 16B = 80KB.
    __shared__ f4 smem[16 * 192 + 16 * 128];

    // ---- stage R rows [w0-64, w0+128): coalesced global read, scattered LDS write.
    {
        f4 t[6];
#pragma unroll
        for (int it = 0; it < 6; ++it) {
            const int cell = tid + it * 512;       // [0, 3072)
            const int row  = cell >> 4;            // [0, 192)
            const int k    = cell & 15;
            int grow = row + (w0 - 64);
            grow = grow < 0 ? 0 : grow;            // clamp; masked at store
            t[it] = *(const f4*)(Rg + (size_t)grow * CC + k * 4);
        }
#pragma unroll
        for (int it = 0; it < 6; ++it) {
            const int cell = tid + it * 512;
            const int row  = cell >> 4;
            const int k    = cell & 15;
            smem[k * 192 + ((row >> 3) + (row & 7) * 24)] = t[it];
        }
    }
    // ---- stage L rows [w0, w0+128)
    {
        f4 t[4];
#pragma unroll
        for (int it = 0; it < 4; ++it) {
            const int cell = tid + it * 512;       // [0, 2048)
            const int row  = cell >> 4;            // [0, 128)
            const int k    = cell & 15;
            t[it] = *(const f4*)(Lg + (size_t)(w0 + row) * CC + k * 4);
        }
#pragma unroll
        for (int it = 0; it < 4; ++it) {
            const int cell = tid + it * 512;
            const int row  = cell >> 4;
            const int k    = cell & 15;
            smem[3072 + k * 128 + ((row >> 3) + (row & 7) * 16)] = t[it];
        }
    }
    __syncthreads();

    const int wv   = tid >> 6;    // wave 0..7
    const int lane = tid & 63;
    const int ta   = lane >> 3;   // 0..7 (w-coarse, stride 16)
    const int tb   = lane & 7;    // 0..7 (d-coarse, stride 8)

    for (int pass = 0; pass < 2; ++pass) {
        const int wp = wv + 8 * pass;          // 0..15
        const int w  = w0 + 16 * ta + wp;      // output w
        const int lrow = 16 * ta + wp;         // L row within tile
        const int lq = 3072 + ((lrow >> 3) + (lrow & 7) * 16);

        int rq[8];
#pragma unroll
        for (int j = 0; j < 8; ++j) {
            const int u = 63 + 16 * ta - 8 * tb + wp - j;   // 0..190
            rq[j] = (u >> 3) + (u & 7) * 24;
        }

        f4 acc[8];
        const f4 zero = {0.f, 0.f, 0.f, 0.f};
#pragma unroll
        for (int j = 0; j < 8; ++j) acc[j] = zero;

#pragma unroll
        for (int k = 0; k < 16; ++k) {
            const f4 lf = smem[lq + k * 128];
#pragma unroll
            for (int j = 0; j < 8; ++j) {
                const f4 rf = smem[k * 192 + rq[j]];
                acc[j] += lf * rf;
            }
        }

        float s[8];
#pragma unroll
        for (int j = 0; j < 8; ++j)
            s[j] = ((acc[j].x + acc[j].y) + (acc[j].z + acc[j].w)) * 0.015625f;

        if (w0 == 0) {   // uniform branch: only first w-tile can have d >= w
#pragma unroll
            for (int j = 0; j < 8; ++j)
                if (8 * tb + j >= w) s[j] = 0.f;
        }

        f4 o0 = {s[0], s[1], s[2], s[3]};
        f4 o1 = {s[4], s[5], s[6], s[7]};
        float* op = Og + (size_t)w * DD + 8 * tb;
        *(f4*)op       = o0;
        *(f4*)(op + 4) = o1;
    }
}

extern "C" void kernel_launch(void* const* d_in, const int* in_sizes, int n_in,
                              void* d_out, int out_size, void* d_ws, size_t ws_size,
                              hipStream_t stream) {
    const float* left  = (const float*)d_in[0];
    const float* right = (const float*)d_in[1];
    float* o = (float*)d_out;

    // 1024 bh * 4 w-tiles; 512 threads; 80KB static LDS -> 2 blocks/CU.
    CostVolume_47433618817551_kernel<<<dim3(4096), dim3(512), 0, stream>>>(
        left, right, o);
}